// Round 18
// baseline (7448.267 us; speedup 1.0000x reference)
//
#include <hip/hip_runtime.h>
#include <stdint.h>

typedef unsigned short u16;
typedef unsigned long long u64;
typedef __attribute__((ext_vector_type(8))) short short8v;
typedef __attribute__((ext_vector_type(4))) float f32x4;

// output layout (floats): out(8,1022,1024) | h_n(2,8,512) | c_n(2,8,512)
#define OUT_HN   8372224
#define OUT_CN   8380416

// ws layout (bytes). zx = seglen*65536 B.
#define WS_FLAGS 0
#define WS_CSB   4096
#define WS_HSB0  36864
#define WS_HSB1  8433664
#define WS_ZX    16830464

__device__ __forceinline__ u16 f2bf(float f) {
  uint32_t u = __float_as_uint(f);
  u += 0x7FFFu + ((u >> 16) & 1u);
  return (u16)(u >> 16);
}
__device__ __forceinline__ float bf2f(u16 v) {
  return __uint_as_float(((uint32_t)v) << 16);
}
__device__ __forceinline__ short8v cvt8(const float* p) {
  float4 a = *(const float4*)p;
  float4 b = *(const float4*)(p + 4);
  short8v r;
  r[0] = (short)f2bf(a.x); r[1] = (short)f2bf(a.y);
  r[2] = (short)f2bf(a.z); r[3] = (short)f2bf(a.w);
  r[4] = (short)f2bf(b.x); r[5] = (short)f2bf(b.y);
  r[6] = (short)f2bf(b.z); r[7] = (short)f2bf(b.w);
  return r;
}

// Zero BOTH h buffers entirely (clears stale tag bits from prior replays),
// write tagged zeros into column 0, zero c state. ~17 MB, ~5us.
__global__ void k_zero(u64* h0, u64* h1, float* c) {
  const size_t n = 8396800 / 8;   // u64s per h buffer
  const size_t stride = (size_t)gridDim.x * blockDim.x;
  for (size_t i = (size_t)blockIdx.x * blockDim.x + threadIdx.x; i < n; i += stride) {
    u64 v = (i < 512) ? 1ull : 0ull;   // col 0: tagged zero (valid, h=~0)
    h0[i] = v;
    h1[i] = v;
  }
  int j = blockIdx.x * blockDim.x + threadIdx.x;
  if (j < 8192) c[j] = 0.f;
}

// stage x col tcol into swizzled xL (R13-proven pattern)
#define STAGE_X(tcol)                                                          \
  {                                                                            \
    _Pragma("unroll")                                                          \
    for (int half = 0; half < 2; ++half) {                                     \
      int g = tid + half * 256;                                                \
      int r = g >> 6, B = g & 63;                                              \
      const float* xr = xf + ((size_t)r * 1024 + (tcol)) * 512 + B * 8;        \
      float4 a = *(const float4*)xr;                                           \
      float4 b = *(const float4*)(xr + 4);                                     \
      short8v v;                                                               \
      v[0] = (short)f2bf(a.x); v[1] = (short)f2bf(a.y);                        \
      v[2] = (short)f2bf(a.z); v[3] = (short)f2bf(a.w);                        \
      v[4] = (short)f2bf(b.x); v[5] = (short)f2bf(b.y);                        \
      v[6] = (short)f2bf(b.z); v[7] = (short)f2bf(b.w);                        \
      *(short8v*)(xL + r * 512 + ((B ^ r) << 3)) = v;                          \
    }                                                                          \
  }

// Precompute zx[dir][sidx][wg16][b*128 + g*32 + j] (bf16) for [s0, s0+seglen).
// Full-GPU batch GEMM (R14-proven, unchanged).
__global__ void k_zx(const float* __restrict__ xf,
                     const float* __restrict__ wihf, const float* __restrict__ wihb,
                     u16* __restrict__ zx, int s0, int seglen)
{
  const int nch  = seglen >> 5;
  const int bid  = blockIdx.x;
  const int chunk = bid % nch;
  const int wg   = (bid / nch) & 15;
  const int dir  = bid / (nch * 16);
  const int tid  = threadIdx.x;
  const int wid  = tid >> 6;
  const int lane = tid & 63;
  const int jbase = wg * 32;
  const float* wih = dir ? wihb : wihf;

  __shared__ u16 xL[8 * 512];
  __shared__ float zL[4 * 8 * 32];

  short8v bih[2][16];
  {
    const int rr = lane & 15;
    const int ko = (lane >> 4) * 8;
    #pragma unroll
    for (int nt = 0; nt < 2; ++nt) {
      const int row = wid * 512 + jbase + nt * 16 + rr;
      #pragma unroll
      for (int kt = 0; kt < 16; ++kt)
        bih[nt][kt] = cvt8(wih + (size_t)row * 512 + kt * 32 + ko);
    }
  }

  const int rB = lane & 7;
  const int q  = lane >> 4;
  const f32x4 fzero = {0.f, 0.f, 0.f, 0.f};

  for (int i = 0; i < 32; ++i) {
    const int sidx = chunk * 32 + i;
    const int gstep = s0 + sidx;
    const int tn = dir ? (1023 - gstep) : gstep;
    STAGE_X(tn);
    __syncthreads();
    f32x4 acc0 = fzero, acc1 = fzero;
    #pragma unroll
    for (int kt = 0; kt < 16; ++kt) {
      short8v ax = *(const short8v*)(xL + rB * 512 + (((kt * 4 + q) ^ rB) << 3));
      acc0 = __builtin_amdgcn_mfma_f32_16x16x32_bf16(ax, bih[0][kt], acc0, 0, 0, 0);
      acc1 = __builtin_amdgcn_mfma_f32_16x16x32_bf16(ax, bih[1][kt], acc1, 0, 0, 0);
    }
    if (lane < 32) {
      #pragma unroll
      for (int r = 0; r < 4; ++r) {
        const int brow = (lane >> 4) * 4 + r;
        zL[wid * 256 + brow * 32 + (lane & 15)]      = acc0[r];
        zL[wid * 256 + brow * 32 + 16 + (lane & 15)] = acc1[r];
      }
    }
    __syncthreads();
    if (tid < 128) {
      const int b = tid >> 4;
      const int r = (tid & 15) * 8;
      const int g = r >> 5;
      const int jj = r & 31;
      short8v v;
      #pragma unroll
      for (int w = 0; w < 8; ++w) v[w] = (short)f2bf(zL[g * 256 + b * 32 + jj + w]);
      *(short8v*)(zx + (((size_t)dir * seglen + sidx) * 16 + wg) * 1024 + tid * 8) = v;
    }
    __syncthreads();
  }
}

// Persistent bidirectional LSTM over steps [s0, s1). 32 blocks x 256 thr.
// R18 protocol — TAGGED-DATA single-round-trip handoff: publisher stores
// each u64 of its h slice with bit0 forced to 1 (fire-and-forget, no vmcnt,
// no flag). Readers poll THEIR OWN 4 column words until all tagged, then
// scatter to swizzled hL. Detection = data arrival (1 LLC traverse) vs the
// R14..R17 flag protocol's 3 serialized traverses. Columns are write-once
// per launch; k_zero clears stale tags. 3 barriers/step (was 4).
__launch_bounds__(256, 1)
__global__ void k_lstm(const float* __restrict__ whhf, const float* __restrict__ whhb,
                       const float* __restrict__ bias0, const float* __restrict__ bias1,
                       const u16* __restrict__ zx,
                       u16* hsb0, u16* hsb1, float* csb, float* out,
                       int s0, int s1, int seglen)
{
  const int tid  = threadIdx.x;
  const int wid  = tid >> 6;     // wave = gate
  const int lane = tid & 63;
  const int dir  = blockIdx.x >> 4;
  const int wg   = blockIdx.x & 15;
  const int jbase = wg * 32;

  const float* whh  = dir ? whhb : whhf;
  const float* bias = dir ? bias1 : bias0;
  u16* hsb = dir ? hsb1 : hsb0;

  __shared__ u16 hL[8 * 512];        // swizzled h column tile (8 KB)
  __shared__ float zL[4 * 8 * 32];   // [gate][b][jj]
  __shared__ u64 hSq[64];            // this WG's h slice (512 B)
  __shared__ u64 zxL[256];           // zx slice for current step (2 KB)

  // W_hh B-fragments from f32 (one-time conversion)
  short8v bhh[2][16];
  {
    const int rr = lane & 15;
    const int ko = (lane >> 4) * 8;
    #pragma unroll
    for (int nt = 0; nt < 2; ++nt) {
      const int row = wid * 512 + jbase + nt * 16 + rr;
      #pragma unroll
      for (int kt = 0; kt < 16; ++kt)
        bhh[nt][kt] = cvt8(whh + (size_t)row * 512 + kt * 32 + ko);
    }
  }

  const int cb = tid >> 5;
  const int cj = tid & 31;
  const float bz0 = bias[0 * 512 + jbase + cj];
  const float bz1 = bias[1 * 512 + jbase + cj];
  const float bz2 = bias[2 * 512 + jbase + cj];
  const float bz3 = bias[3 * 512 + jbase + cj];
  float* cp = csb + dir * 4096 + cb * 512 + jbase + cj;
  float c_state = *cp;               // zeroed by k_zero; carried across segments

  const int rB = lane & 7;
  const int q  = lane >> 4;
  const f32x4 fzero = {0.f, 0.f, 0.f, 0.f};
  const u16* zx16 = (const u16*)zxL;
  u16* hS = (u16*)hSq;

  for (int gstep = s0; gstep < s1; ++gstep) {
    // all threads: prefetch zx slice (independent of the h handoff)
    {
      const u64* zp = (const u64*)(zx + (((size_t)dir * seglen + (gstep - s0)) * 16 + wg) * 1024);
      zxL[tid] = zp[tid];
    }
    // poll OWN 4 column words until all carry the valid tag (bit0).
    // Single LLC round trip: detection IS the data load. Bounded.
    u64 d0, d1, d2, d3;
    {
      const u64* hc = (const u64*)(hsb + (size_t)gstep * 4096);
      int guard = 0;
      for (;;) {
        d0 = __hip_atomic_load(hc + 4 * tid + 0, __ATOMIC_RELAXED, __HIP_MEMORY_SCOPE_AGENT);
        d1 = __hip_atomic_load(hc + 4 * tid + 1, __ATOMIC_RELAXED, __HIP_MEMORY_SCOPE_AGENT);
        d2 = __hip_atomic_load(hc + 4 * tid + 2, __ATOMIC_RELAXED, __HIP_MEMORY_SCOPE_AGENT);
        d3 = __hip_atomic_load(hc + 4 * tid + 3, __ATOMIC_RELAXED, __HIP_MEMORY_SCOPE_AGENT);
        if (((d0 & d1 & d2 & d3) & 1ull) || ++guard >= (1 << 15)) break;
      }
    }
    // scatter into swizzled hL
    {
      union { u64 qq[2]; short8v v; } p0, p1;
      p0.qq[0] = d0; p0.qq[1] = d1;
      p1.qq[0] = d2; p1.qq[1] = d3;
      int G0 = 2 * tid, G1 = 2 * tid + 1;
      int r0 = G0 >> 6, B0 = G0 & 63;
      int r1 = G1 >> 6, B1 = G1 & 63;
      *(short8v*)(hL + r0 * 512 + ((B0 ^ r0) << 3)) = p0.v;
      *(short8v*)(hL + r1 * 512 + ((B1 ^ r1) << 3)) = p1.v;
    }
    __syncthreads();   // A: hL + zxL ready
    // h-projection from LDS (plain chains — R14-proven)
    f32x4 acc0 = fzero, acc1 = fzero;
    #pragma unroll
    for (int kt = 0; kt < 16; ++kt) {
      short8v ah = *(const short8v*)(hL + rB * 512 + (((kt * 4 + q) ^ rB) << 3));
      acc0 = __builtin_amdgcn_mfma_f32_16x16x32_bf16(ah, bhh[0][kt], acc0, 0, 0, 0);
      acc1 = __builtin_amdgcn_mfma_f32_16x16x32_bf16(ah, bhh[1][kt], acc1, 0, 0, 0);
    }
    if (lane < 32) {
      #pragma unroll
      for (int r = 0; r < 4; ++r) {
        const int brow = (lane >> 4) * 4 + r;
        zL[wid * 256 + brow * 32 + (lane & 15)]      = acc0[r];
        zL[wid * 256 + brow * 32 + 16 + (lane & 15)] = acc1[r];
      }
    }
    __syncthreads();   // B
    // gates: z = h-part (zL) + precomputed x-part (zxL) + bias
    {
      float zi = zL[0 * 256 + cb * 32 + cj] + bz0 + bf2f(zx16[cb * 128 +  0 + cj]);
      float zf = zL[1 * 256 + cb * 32 + cj] + bz1 + bf2f(zx16[cb * 128 + 32 + cj]);
      float zg = zL[2 * 256 + cb * 32 + cj] + bz2 + bf2f(zx16[cb * 128 + 64 + cj]);
      float zo = zL[3 * 256 + cb * 32 + cj] + bz3 + bf2f(zx16[cb * 128 + 96 + cj]);
      float si = 1.f / (1.f + __expf(-zi));
      float sf = 1.f / (1.f + __expf(-zf));
      float so = 1.f / (1.f + __expf(-zo));
      float ag = fabsf(zg); float eg = __expf(-2.f * ag);
      float tg = (1.f - eg) / (1.f + eg); tg = copysignf(tg, zg);
      c_state = sf * c_state + si * tg;
      float ac = fabsf(c_state); float ec = __expf(-2.f * ac);
      float tc = (1.f - ec) / (1.f + ec); tc = copysignf(tc, c_state);
      float h = so * tc;
      hS[cb * 32 + cj] = f2bf(h);
      if (gstep == 1023) {
        out[OUT_HN + dir * 4096 + cb * 512 + jbase + cj] = h;
        out[OUT_CN + dir * 4096 + cb * 512 + jbase + cj] = c_state;
      }
    }
    __syncthreads();   // C: hS complete
    // wave 0: publish h slice with tag bits — fire-and-forget (no vmcnt,
    // no flag). Readers detect via the data itself.
    if (tid < 64) {
      const int pb = tid >> 3;
      const int pt = tid & 7;
      u64 hv = hSq[pb * 8 + pt] | 1ull;   // bit0 = valid tag (<=1 ulp noise)
      u64* dst = (u64*)(hsb + ((size_t)(gstep + 1) * 8 + pb) * 512 + jbase + 4 * pt);
      __hip_atomic_store(dst, hv, __ATOMIC_RELAXED, __HIP_MEMORY_SCOPE_AGENT);
    }
  }
  *cp = c_state;   // carry c across segments
}

// Neighbor-average epilogue — R9-proven (order is int32 on device).
__global__ void k_combine(const u16* __restrict__ hsb0, const u16* __restrict__ hsb1,
                          const int* __restrict__ cidx, const int* __restrict__ cmask,
                          const int* __restrict__ order, float* __restrict__ out)
{
  const int tid = threadIdx.x;
  const int b = blockIdx.x / 1022;
  const int s = 1 + (blockIdx.x % 1022);
  __shared__ int sidx[8];
  __shared__ float smask[8];
  __shared__ int rsh;
  if (tid == 0) rsh = order[b];
  __syncthreads();
  const int r = rsh;
  if (tid < 8) {
    size_t base = ((size_t)r * 1024 + s) * 8 + tid;
    sidx[tid] = cidx[base];
    smask[tid] = (float)cmask[base];
  }
  __syncthreads();
  float cnt = 0.f;
  #pragma unroll
  for (int k = 0; k < 8; ++k) cnt += smask[k];
  const float inv = 1.f / (1.f + cnt);

  const int col0 = tid * 4;
  const bool isF = col0 < 512;
  const int cloc = isF ? col0 : col0 - 512;
  const u16* hb = isF ? hsb0 : hsb1;

  float v0, v1, v2, v3;
  {
    size_t ci2 = isF ? (size_t)(s + 1) : (size_t)(1024 - s);
    ushort4 qv = *(const ushort4*)(hb + (ci2 * 8 + b) * 512 + cloc);
    v0 = bf2f(qv.x); v1 = bf2f(qv.y); v2 = bf2f(qv.z); v3 = bf2f(qv.w);
  }
  #pragma unroll
  for (int k = 0; k < 8; ++k) {
    float m = smask[k];
    if (m != 0.f) {
      int sp = sidx[k];
      size_t ci2 = isF ? (size_t)(sp + 1) : (size_t)(1024 - sp);
      ushort4 qv = *(const ushort4*)(hb + (ci2 * 8 + b) * 512 + cloc);
      v0 += m * bf2f(qv.x); v1 += m * bf2f(qv.y); v2 += m * bf2f(qv.z); v3 += m * bf2f(qv.w);
    }
  }
  size_t ob = ((size_t)r * 1022 + (s - 1)) * 1024 + col0;
  float4 ov; ov.x = v0 * inv; ov.y = v1 * inv; ov.z = v2 * inv; ov.w = v3 * inv;
  *(float4*)(out + ob) = ov;
}

extern "C" void kernel_launch(void* const* d_in, const int* in_sizes, int n_in,
                              void* d_out, int out_size, void* d_ws, size_t ws_size,
                              hipStream_t stream)
{
  const float* x      = (const float*)d_in[0];
  const int*   cidx   = (const int*)d_in[1];
  const int*   cmask  = (const int*)d_in[2];
  const int*   order  = (const int*)d_in[3];   // int64 in reference -> int32 on device
  const float* wihf = (const float*)d_in[4];
  const float* whhf = (const float*)d_in[5];
  const float* bf   = (const float*)d_in[6];
  const float* wihb = (const float*)d_in[7];
  const float* whhb = (const float*)d_in[8];
  const float* bb   = (const float*)d_in[9];
  float* out = (float*)d_out;

  char* ws = (char*)d_ws;
  float* CSB = (float*)(ws + WS_CSB);
  u16* HSB0 = (u16*)(ws + WS_HSB0);
  u16* HSB1 = (u16*)(ws + WS_HSB1);
  u16* ZX   = (u16*)(ws + WS_ZX);

  const int seglen = (ws_size >= (size_t)WS_ZX + 1024ull * 65536) ? 1024 : 128;

  hipLaunchKernelGGL(k_zero, dim3(1024), dim3(256), 0, stream,
                     (u64*)HSB0, (u64*)HSB1, CSB);

  for (int s0 = 0; s0 < 1024; s0 += seglen) {
    hipLaunchKernelGGL(k_zx, dim3(2 * 16 * (seglen >> 5)), dim3(256), 0, stream,
                       x, wihf, wihb, ZX, s0, seglen);
    hipLaunchKernelGGL(k_lstm, dim3(32), dim3(256), 0, stream,
                       whhf, whhb, bf, bb, ZX, HSB0, HSB1, CSB, out,
                       s0, s0 + seglen, seglen);
  }

  hipLaunchKernelGGL(k_combine, dim3(8 * 1022), dim3(256), 0, stream,
                     HSB0, HSB1, cidx, cmask, order, out);
}

// Round 19
// 2931.877 us; speedup vs baseline: 2.5404x; 2.5404x over previous
//
#include <hip/hip_runtime.h>
#include <stdint.h>

typedef unsigned short u16;
typedef unsigned long long u64;
typedef __attribute__((ext_vector_type(8))) short short8v;
typedef __attribute__((ext_vector_type(4))) float f32x4;

// output layout (floats): out(8,1022,1024) | h_n(2,8,512) | c_n(2,8,512)
#define OUT_HN   8372224
#define OUT_CN   8380416

// ws layout (bytes). zx = seglen*65536 B.
#define WS_FLAGS 0
#define WS_CSB   4096
#define WS_HSB0  36864
#define WS_HSB1  8433664
#define WS_ZX    16830464

__device__ __forceinline__ u16 f2bf(float f) {
  uint32_t u = __float_as_uint(f);
  u += 0x7FFFu + ((u >> 16) & 1u);
  return (u16)(u >> 16);
}
__device__ __forceinline__ float bf2f(u16 v) {
  return __uint_as_float(((uint32_t)v) << 16);
}
__device__ __forceinline__ short8v cvt8(const float* p) {
  float4 a = *(const float4*)p;
  float4 b = *(const float4*)(p + 4);
  short8v r;
  r[0] = (short)f2bf(a.x); r[1] = (short)f2bf(a.y);
  r[2] = (short)f2bf(a.z); r[3] = (short)f2bf(a.w);
  r[4] = (short)f2bf(b.x); r[5] = (short)f2bf(b.y);
  r[6] = (short)f2bf(b.z); r[7] = (short)f2bf(b.w);
  return r;
}

__global__ void k_init(uint32_t* flags) {
  if (threadIdx.x < 64) flags[threadIdx.x] = 0;
}

// zero h col 0 (both dirs) and c state
__global__ void k_zero(u16* h0, u16* h1, float* c) {
  int i = blockIdx.x * blockDim.x + threadIdx.x;   // 8192 threads
  if (i < 4096) { h0[i] = 0; h1[i] = 0; }
  if (i < 8192) c[i] = 0.f;
}

// stage x col tcol into swizzled xL (R13-proven pattern)
#define STAGE_X(tcol)                                                          \
  {                                                                            \
    _Pragma("unroll")                                                          \
    for (int half = 0; half < 2; ++half) {                                     \
      int g = tid + half * 256;                                                \
      int r = g >> 6, B = g & 63;                                              \
      const float* xr = xf + ((size_t)r * 1024 + (tcol)) * 512 + B * 8;        \
      float4 a = *(const float4*)xr;                                           \
      float4 b = *(const float4*)(xr + 4);                                     \
      short8v v;                                                               \
      v[0] = (short)f2bf(a.x); v[1] = (short)f2bf(a.y);                        \
      v[2] = (short)f2bf(a.z); v[3] = (short)f2bf(a.w);                        \
      v[4] = (short)f2bf(b.x); v[5] = (short)f2bf(b.y);                        \
      v[6] = (short)f2bf(b.z); v[7] = (short)f2bf(b.w);                        \
      *(short8v*)(xL + r * 512 + ((B ^ r) << 3)) = v;                          \
    }                                                                          \
  }

// Precompute zx[dir][sidx][wg16][b*128 + g*32 + j] (bf16) for [s0, s0+seglen).
// Full-GPU batch GEMM (R14-proven, unchanged).
__global__ void k_zx(const float* __restrict__ xf,
                     const float* __restrict__ wihf, const float* __restrict__ wihb,
                     u16* __restrict__ zx, int s0, int seglen)
{
  const int nch  = seglen >> 5;
  const int bid  = blockIdx.x;
  const int chunk = bid % nch;
  const int wg   = (bid / nch) & 15;
  const int dir  = bid / (nch * 16);
  const int tid  = threadIdx.x;
  const int wid  = tid >> 6;
  const int lane = tid & 63;
  const int jbase = wg * 32;
  const float* wih = dir ? wihb : wihf;

  __shared__ u16 xL[8 * 512];
  __shared__ float zL[4 * 8 * 32];

  short8v bih[2][16];
  {
    const int rr = lane & 15;
    const int ko = (lane >> 4) * 8;
    #pragma unroll
    for (int nt = 0; nt < 2; ++nt) {
      const int row = wid * 512 + jbase + nt * 16 + rr;
      #pragma unroll
      for (int kt = 0; kt < 16; ++kt)
        bih[nt][kt] = cvt8(wih + (size_t)row * 512 + kt * 32 + ko);
    }
  }

  const int rB = lane & 7;
  const int q  = lane >> 4;
  const f32x4 fzero = {0.f, 0.f, 0.f, 0.f};

  for (int i = 0; i < 32; ++i) {
    const int sidx = chunk * 32 + i;
    const int gstep = s0 + sidx;
    const int tn = dir ? (1023 - gstep) : gstep;
    STAGE_X(tn);
    __syncthreads();
    f32x4 acc0 = fzero, acc1 = fzero;
    #pragma unroll
    for (int kt = 0; kt < 16; ++kt) {
      short8v ax = *(const short8v*)(xL + rB * 512 + (((kt * 4 + q) ^ rB) << 3));
      acc0 = __builtin_amdgcn_mfma_f32_16x16x32_bf16(ax, bih[0][kt], acc0, 0, 0, 0);
      acc1 = __builtin_amdgcn_mfma_f32_16x16x32_bf16(ax, bih[1][kt], acc1, 0, 0, 0);
    }
    if (lane < 32) {
      #pragma unroll
      for (int r = 0; r < 4; ++r) {
        const int brow = (lane >> 4) * 4 + r;
        zL[wid * 256 + brow * 32 + (lane & 15)]      = acc0[r];
        zL[wid * 256 + brow * 32 + 16 + (lane & 15)] = acc1[r];
      }
    }
    __syncthreads();
    if (tid < 128) {
      const int b = tid >> 4;
      const int r = (tid & 15) * 8;
      const int g = r >> 5;
      const int jj = r & 31;
      short8v v;
      #pragma unroll
      for (int w = 0; w < 8; ++w) v[w] = (short)f2bf(zL[g * 256 + b * 32 + jj + w]);
      *(short8v*)(zx + (((size_t)dir * seglen + sidx) * 16 + wg) * 1024 + tid * 8) = v;
    }
    __syncthreads();
  }
}

// Persistent bidirectional LSTM over steps [s0, s1). 32 blocks x 256 thr.
// R19 = R14's proven protocol (narrow 16-flag poll, cooperative column load
// -> swizzled hL -> ds_read fragments, plain MFMA chains, serial publish
// with vmcnt+flag) with the column load and publish widened from 8B atomic
// (dwordx2 sc1) to 16B inline-asm dwordx4 sc1 — identical device-scope
// cache policy, HALF the LLC transactions on the two LLC-bound legs.
__launch_bounds__(256, 1)
__global__ void k_lstm(const float* __restrict__ whhf, const float* __restrict__ whhb,
                       const float* __restrict__ bias0, const float* __restrict__ bias1,
                       const u16* __restrict__ zx,
                       u16* hsb0, u16* hsb1, float* csb, float* out,
                       uint32_t* flags, int s0, int s1, int seglen)
{
  const int tid  = threadIdx.x;
  const int wid  = tid >> 6;     // wave = gate
  const int lane = tid & 63;
  const int dir  = blockIdx.x >> 4;
  const int wg   = blockIdx.x & 15;
  const int jbase = wg * 32;

  const float* whh  = dir ? whhb : whhf;
  const float* bias = dir ? bias1 : bias0;
  u16* hsb = dir ? hsb1 : hsb0;
  uint32_t* fl = flags + dir * 16;

  __shared__ u16 hL[8 * 512];        // swizzled h column tile (8 KB)
  __shared__ float zL[4 * 8 * 32];   // [gate][b][jj]
  __shared__ u16 hS[8 * 32];         // this WG's h slice
  __shared__ u64 zxL[256];           // zx slice for current step (2 KB)

  // W_hh B-fragments from f32 (one-time conversion)
  short8v bhh[2][16];
  {
    const int rr = lane & 15;
    const int ko = (lane >> 4) * 8;
    #pragma unroll
    for (int nt = 0; nt < 2; ++nt) {
      const int row = wid * 512 + jbase + nt * 16 + rr;
      #pragma unroll
      for (int kt = 0; kt < 16; ++kt)
        bhh[nt][kt] = cvt8(whh + (size_t)row * 512 + kt * 32 + ko);
    }
  }

  const int cb = tid >> 5;
  const int cj = tid & 31;
  const float bz0 = bias[0 * 512 + jbase + cj];
  const float bz1 = bias[1 * 512 + jbase + cj];
  const float bz2 = bias[2 * 512 + jbase + cj];
  const float bz3 = bias[3 * 512 + jbase + cj];
  float* cp = csb + dir * 4096 + cb * 512 + jbase + cj;
  float c_state = *cp;               // zeroed by k_zero; carried across segments

  const int rB = lane & 7;
  const int q  = lane >> 4;
  const f32x4 fzero = {0.f, 0.f, 0.f, 0.f};
  const u16* zx16 = (const u16*)zxL;

  for (int gstep = s0; gstep < s1; ++gstep) {
    // all threads: prefetch zx slice (independent of flags)
    {
      const u64* zp = (const u64*)(zx + (((size_t)dir * seglen + (gstep - s0)) * 16 + wg) * 1024);
      zxL[tid] = zp[tid];
    }
    // wave 0: narrow poll of 16 per-WG flags (bounded)
    if (tid < 16) {
      int guard = 0;
      while (__hip_atomic_load(&fl[tid], __ATOMIC_RELAXED, __HIP_MEMORY_SCOPE_AGENT)
             < (uint32_t)gstep && ++guard < (1 << 15)) { }
    }
    __syncthreads();   // A: column published everywhere, zxL ready
    // cooperative column load: 2 x 16B device-scope loads per thread
    // (512 LLC transactions/WG vs R14's 1024), scatter into swizzled hL
    {
      const u16* base = hsb + (size_t)gstep * 4096 + tid * 16;
      short8v v0, v1;
      asm volatile("global_load_dwordx4 %0, %1, off sc1"
                   : "=v"(v0) : "v"(base));
      asm volatile("global_load_dwordx4 %0, %1, off offset:16 sc1"
                   : "=v"(v1) : "v"(base));
      asm volatile("s_waitcnt vmcnt(0)" ::: "memory");
      int G0 = 2 * tid, G1 = 2 * tid + 1;
      int r0 = G0 >> 6, B0 = G0 & 63;
      int r1 = G1 >> 6, B1 = G1 & 63;
      *(short8v*)(hL + r0 * 512 + ((B0 ^ r0) << 3)) = v0;
      *(short8v*)(hL + r1 * 512 + ((B1 ^ r1) << 3)) = v1;
    }
    __syncthreads();   // B
    // h-projection from LDS (plain chains — R14-proven)
    f32x4 acc0 = fzero, acc1 = fzero;
    #pragma unroll
    for (int kt = 0; kt < 16; ++kt) {
      short8v ah = *(const short8v*)(hL + rB * 512 + (((kt * 4 + q) ^ rB) << 3));
      acc0 = __builtin_amdgcn_mfma_f32_16x16x32_bf16(ah, bhh[0][kt], acc0, 0, 0, 0);
      acc1 = __builtin_amdgcn_mfma_f32_16x16x32_bf16(ah, bhh[1][kt], acc1, 0, 0, 0);
    }
    if (lane < 32) {
      #pragma unroll
      for (int r = 0; r < 4; ++r) {
        const int brow = (lane >> 4) * 4 + r;
        zL[wid * 256 + brow * 32 + (lane & 15)]      = acc0[r];
        zL[wid * 256 + brow * 32 + 16 + (lane & 15)] = acc1[r];
      }
    }
    __syncthreads();   // C
    // gates: z = h-part (zL) + precomputed x-part (zxL) + bias
    {
      float zi = zL[0 * 256 + cb * 32 + cj] + bz0 + bf2f(zx16[cb * 128 +  0 + cj]);
      float zf = zL[1 * 256 + cb * 32 + cj] + bz1 + bf2f(zx16[cb * 128 + 32 + cj]);
      float zg = zL[2 * 256 + cb * 32 + cj] + bz2 + bf2f(zx16[cb * 128 + 64 + cj]);
      float zo = zL[3 * 256 + cb * 32 + cj] + bz3 + bf2f(zx16[cb * 128 + 96 + cj]);
      float si = 1.f / (1.f + __expf(-zi));
      float sf = 1.f / (1.f + __expf(-zf));
      float so = 1.f / (1.f + __expf(-zo));
      float ag = fabsf(zg); float eg = __expf(-2.f * ag);
      float tg = (1.f - eg) / (1.f + eg); tg = copysignf(tg, zg);
      c_state = sf * c_state + si * tg;
      float ac = fabsf(c_state); float ec = __expf(-2.f * ac);
      float tc = (1.f - ec) / (1.f + ec); tc = copysignf(tc, c_state);
      float h = so * tc;
      hS[cb * 32 + cj] = f2bf(h);
      if (gstep == 1023) {
        out[OUT_HN + dir * 4096 + cb * 512 + jbase + cj] = h;
        out[OUT_CN + dir * 4096 + cb * 512 + jbase + cj] = c_state;
      }
    }
    __syncthreads();   // D: hS complete
    // wave 0 lanes 0..31: publish h slice as 16B device-scope stores
    // (32 LLC transactions vs R14's 64), one vmcnt(0), then flag.
    if (tid < 32) {
      const int pb = tid >> 2;          // batch
      const int pt = tid & 3;           // 16B unit within 32 units
      short8v hv = *(const short8v*)(hS + pb * 32 + 8 * pt);
      u16* dst = hsb + ((size_t)(gstep + 1) * 8 + pb) * 512 + jbase + 8 * pt;
      asm volatile("global_store_dwordx4 %0, %1, off sc1"
                   :: "v"(dst), "v"(hv) : "memory");
      asm volatile("s_waitcnt vmcnt(0)" ::: "memory");  // slice at LLC
    }
    if (tid == 0) {
      __hip_atomic_store(&fl[wg], (uint32_t)(gstep + 1), __ATOMIC_RELAXED,
                         __HIP_MEMORY_SCOPE_AGENT);
    }
  }
  *cp = c_state;   // carry c across segments
}

// Neighbor-average epilogue — R9-proven (order is int32 on device).
__global__ void k_combine(const u16* __restrict__ hsb0, const u16* __restrict__ hsb1,
                          const int* __restrict__ cidx, const int* __restrict__ cmask,
                          const int* __restrict__ order, float* __restrict__ out)
{
  const int tid = threadIdx.x;
  const int b = blockIdx.x / 1022;
  const int s = 1 + (blockIdx.x % 1022);
  __shared__ int sidx[8];
  __shared__ float smask[8];
  __shared__ int rsh;
  if (tid == 0) rsh = order[b];
  __syncthreads();
  const int r = rsh;
  if (tid < 8) {
    size_t base = ((size_t)r * 1024 + s) * 8 + tid;
    sidx[tid] = cidx[base];
    smask[tid] = (float)cmask[base];
  }
  __syncthreads();
  float cnt = 0.f;
  #pragma unroll
  for (int k = 0; k < 8; ++k) cnt += smask[k];
  const float inv = 1.f / (1.f + cnt);

  const int col0 = tid * 4;
  const bool isF = col0 < 512;
  const int cloc = isF ? col0 : col0 - 512;
  const u16* hb = isF ? hsb0 : hsb1;

  float v0, v1, v2, v3;
  {
    size_t ci2 = isF ? (size_t)(s + 1) : (size_t)(1024 - s);
    ushort4 qv = *(const ushort4*)(hb + (ci2 * 8 + b) * 512 + cloc);
    v0 = bf2f(qv.x); v1 = bf2f(qv.y); v2 = bf2f(qv.z); v3 = bf2f(qv.w);
  }
  #pragma unroll
  for (int k = 0; k < 8; ++k) {
    float m = smask[k];
    if (m != 0.f) {
      int sp = sidx[k];
      size_t ci2 = isF ? (size_t)(sp + 1) : (size_t)(1024 - sp);
      ushort4 qv = *(const ushort4*)(hb + (ci2 * 8 + b) * 512 + cloc);
      v0 += m * bf2f(qv.x); v1 += m * bf2f(qv.y); v2 += m * bf2f(qv.z); v3 += m * bf2f(qv.w);
    }
  }
  size_t ob = ((size_t)r * 1022 + (s - 1)) * 1024 + col0;
  float4 ov; ov.x = v0 * inv; ov.y = v1 * inv; ov.z = v2 * inv; ov.w = v3 * inv;
  *(float4*)(out + ob) = ov;
}

extern "C" void kernel_launch(void* const* d_in, const int* in_sizes, int n_in,
                              void* d_out, int out_size, void* d_ws, size_t ws_size,
                              hipStream_t stream)
{
  const float* x      = (const float*)d_in[0];
  const int*   cidx   = (const int*)d_in[1];
  const int*   cmask  = (const int*)d_in[2];
  const int*   order  = (const int*)d_in[3];   // int64 in reference -> int32 on device
  const float* wihf = (const float*)d_in[4];
  const float* whhf = (const float*)d_in[5];
  const float* bf   = (const float*)d_in[6];
  const float* wihb = (const float*)d_in[7];
  const float* whhb = (const float*)d_in[8];
  const float* bb   = (const float*)d_in[9];
  float* out = (float*)d_out;

  char* ws = (char*)d_ws;
  uint32_t* FLAGS = (uint32_t*)(ws + WS_FLAGS);
  float* CSB = (float*)(ws + WS_CSB);
  u16* HSB0 = (u16*)(ws + WS_HSB0);
  u16* HSB1 = (u16*)(ws + WS_HSB1);
  u16* ZX   = (u16*)(ws + WS_ZX);

  const int seglen = (ws_size >= (size_t)WS_ZX + 1024ull * 65536) ? 1024 : 128;

  hipLaunchKernelGGL(k_init, dim3(1), dim3(64), 0, stream, FLAGS);
  hipLaunchKernelGGL(k_zero, dim3(32), dim3(256), 0, stream, HSB0, HSB1, CSB);

  for (int s0 = 0; s0 < 1024; s0 += seglen) {
    hipLaunchKernelGGL(k_zx, dim3(2 * 16 * (seglen >> 5)), dim3(256), 0, stream,
                       x, wihf, wihb, ZX, s0, seglen);
    hipLaunchKernelGGL(k_lstm, dim3(32), dim3(256), 0, stream,
                       whhf, whhb, bf, bb, ZX, HSB0, HSB1, CSB, out, FLAGS,
                       s0, s0 + seglen, seglen);
  }

  hipLaunchKernelGGL(k_combine, dim3(8 * 1022), dim3(256), 0, stream,
                     HSB0, HSB1, cidx, cmask, order, out);
}